// Round 6
// baseline (279.740 us; speedup 1.0000x reference)
//
#include <hip/hip_runtime.h>
#include <hip/hip_bf16.h>

// AttnBlock2D decoupled-GEMM pipeline, R6. B=4, C=512, N=4096 per batch.
//   kt[(b,i)][c] = (x.Wk + bk) * (log2e/sqrt(512))
//   qt[(b,j)][c] = x.Wq + bq
//   vc[c][(b,j)] = x.Wv + bv
//   P_h[b][i][jl] = exp2(kt.qt^T)   (unnormalized), Lpart row partials
//   otab[(b,i)][h*512+c] = P_h.V    (bf16 partial halves side by side)
//   out[b][co][n] = (Wo_dup . otab^T)(K=1024) * linv + bo
// R6: all GEMMs on an m201-style fine 8-phase 256^2/BK=64/8-wave core
// (per-phase {ds-read quadrant | 1 half-tile stage | bar | lgkm0 | 16 MFMA | bar},
//  counted vmcnt(2) at p1/p5 only). XCD-aware 1D grids (T1) kept from R5.

typedef __attribute__((ext_vector_type(4))) float f32x4;
typedef __attribute__((ext_vector_type(8))) short short8;
typedef __attribute__((ext_vector_type(4))) short short4v;

#define QSCALE 0.06376639774f   // (1/sqrt(512)) * log2(e)
#define FENCE asm volatile("" ::: "memory")
#define SBAR  do { FENCE; __builtin_amdgcn_s_barrier(); FENCE; } while (0)
#define LGKM0 asm volatile("s_waitcnt lgkmcnt(0)" ::: "memory")

__device__ __forceinline__ unsigned short f2bf(float f) {
  unsigned u = __builtin_bit_cast(unsigned, f);
  unsigned r = (u + 0x7FFFu + ((u >> 16) & 1u)) >> 16;   // RNE
  return (unsigned short)r;
}

__device__ __forceinline__ void gll16(const void* g, void* l) {
  __builtin_amdgcn_global_load_lds((const __attribute__((address_space(1))) void*)g,
                                   (__attribute__((address_space(3))) void*)l, 16, 0, 0);
}

#define MFMA_BF16(d, va, vb) \
  d = __builtin_amdgcn_mfma_f32_16x16x32_bf16(va, vb, d, 0, 0, 0)

// ============== fine 8-phase 256^2 core (8 waves, BK=64, 2 K-tiles/iter) ==============
// LDS 128KB: A region 64KB [buf(2)][half(2)][128 rows x 128B swz], B region same.
// Stage targets per phase: p1:B1(T+1) p2:A0(T+1) p3:A1(T+1) p4:B0(T+2)
//                          p5:B1(T+2) p6:A0(T+2) p7:A1(T+2) p8:B0(T+3)
// vmcnt(2) before p1/p5 == oldest full K-tile landed (2 loads/stage, 5 stages out).
__device__ __forceinline__ void gemm256_fine(
    const short* __restrict__ A, int lda,
    const short* __restrict__ B, int ldb,
    int nkt, char* sm, f32x4 (&acc)[8][4]) {
  const int tid = threadIdx.x, w = tid >> 6, lane = tid & 63;
  const int g = lane >> 4, l15 = lane & 15;
  const int wm = w >> 2, wn = w & 3;
  const int swz = (l15 & 7) << 4;
  const int brow = (wn & 1) << 6;
  const char* SAb = sm + (wm << 14);
  const char* SBb = sm + 65536 + ((wn >> 1) << 14);

  auto stage = [&](int mat, int half, int t) {
    if (t >= nkt) return;
    char* dst = sm + mat * 65536 + ((t & 1) << 15) + (half << 14) + (w << 10);
    const short* src = mat ? B : A;
    const int ld = mat ? ldb : lda;
    const char* gs = (const char*)src + ((size_t)(half * 128) * ld + (size_t)t * 64) * 2;
#pragma unroll
    for (int q = 0; q < 2; ++q) {
      int o = (q << 13) | (w << 10) | (lane << 4);
      int row = o >> 7, cb = (o & 127) ^ ((row & 7) << 4);
      gll16(gs + (size_t)row * (ld * 2) + cb, dst + (q << 13));
    }
  };
  auto rdA = [&](short8* a4, int mf0, int ks, int buf) {
    const char* SA = SAb + (buf << 15);
#pragma unroll
    for (int i = 0; i < 4; ++i)
      a4[i] = *(const short8*)(SA + ((mf0 + i) * 16 + l15) * 128 + ((ks * 64 + g * 16) ^ swz));
  };
  auto rdB = [&](short8* b4, int ks, int buf) {
    const char* SB = SBb + (buf << 15);
#pragma unroll
    for (int nf = 0; nf < 4; ++nf)
      b4[nf] = *(const short8*)(SB + (brow + nf * 16 + l15) * 128 + ((ks * 64 + g * 16) ^ swz));
  };
  auto mm = [&](short8* a4, short8* b4, int mf0) {
    __builtin_amdgcn_s_setprio(1);
#pragma unroll
    for (int i = 0; i < 4; ++i)
#pragma unroll
      for (int nf = 0; nf < 4; ++nf)
        MFMA_BF16(acc[mf0 + i][nf], a4[i], b4[nf]);
    __builtin_amdgcn_s_setprio(0);
  };

  // prologue: B0(0) B1(0) A0(0) A1(0) B0(1)  (order matters for the vmcnt ledger)
  stage(1, 0, 0); stage(1, 1, 0); stage(0, 0, 0); stage(0, 1, 0); stage(1, 0, 1);

  for (int T = 0; T < nkt; T += 2) {           // tile T -> buf0, T+1 -> buf1
    short8 a[8], bb[4];
    // p1: tile T, ks0, mf0-3
    asm volatile("s_waitcnt vmcnt(2)" ::: "memory"); SBAR;
    rdA(a, 0, 0, 0); rdB(bb, 0, 0); stage(1, 1, T + 1);
    SBAR; LGKM0; mm(a, bb, 0); SBAR;
    // p2: tile T, ks0, mf4-7
    rdA(a + 4, 4, 0, 0); stage(0, 0, T + 1);
    SBAR; LGKM0; mm(a + 4, bb, 4); SBAR;
    // p3: tile T, ks1, mf0-3
    rdA(a, 0, 1, 0); rdB(bb, 1, 0); stage(0, 1, T + 1);
    SBAR; LGKM0; mm(a, bb, 0); SBAR;
    // p4: tile T, ks1, mf4-7
    rdA(a + 4, 4, 1, 0); stage(1, 0, T + 2);
    SBAR; LGKM0; mm(a + 4, bb, 4); SBAR;
    // p5: tile T+1, ks0, mf0-3
    if (T + 2 < nkt) { asm volatile("s_waitcnt vmcnt(2)" ::: "memory"); }
    else             { asm volatile("s_waitcnt vmcnt(0)" ::: "memory"); }
    SBAR;
    rdA(a, 0, 0, 1); rdB(bb, 0, 1); stage(1, 1, T + 2);
    SBAR; LGKM0; mm(a, bb, 0); SBAR;
    // p6: tile T+1, ks0, mf4-7
    rdA(a + 4, 4, 0, 1); stage(0, 0, T + 2);
    SBAR; LGKM0; mm(a + 4, bb, 4); SBAR;
    // p7: tile T+1, ks1, mf0-3
    rdA(a, 0, 1, 1); rdB(bb, 1, 1); stage(0, 1, T + 2);
    SBAR; LGKM0; mm(a, bb, 0); SBAR;
    // p8: tile T+1, ks1, mf4-7
    rdA(a + 4, 4, 1, 1); stage(1, 0, T + 3);
    SBAR; LGKM0; mm(a + 4, bb, 4); SBAR;
  }
}

// 256-tile bounce flush: sm holds 256 rows x 512B (swizzled); 16B coalesced stores.
#define BOUNCE256_WRITE(smp, row, colb, val) \
  *(short*)((smp) + (row) * 512 + (((colb)) ^ (((row) & 7) << 4))) = (val)

__device__ __forceinline__ void bounce256_flush(const char* smp, short* gbase,
                                                int pitch /*shorts*/) {
  const int tid = threadIdx.x;
  SBAR;
#pragma unroll
  for (int it = 0; it < 16; ++it) {
    int row = (tid >> 5) + it * 16;
    short8 v = *(const short8*)(smp + row * 512 + (((tid & 31) * 16) ^ ((row & 7) << 4)));
    *(short8*)(gbase + (size_t)row * pitch + (tid & 31) * 8) = v;
  }
}

// ---------------------------------------------------------------- cvt weights
__global__ __launch_bounds__(256) void cvt_w_kernel(
    const float* __restrict__ wk, const float* __restrict__ wq,
    const float* __restrict__ wv, const float* __restrict__ wo,
    short* __restrict__ o) {
  int z = blockIdx.y;
  const float* s = (z == 0) ? wk : (z == 1) ? wq : (z == 2) ? wv : wo;
  int i = blockIdx.x * 256 + threadIdx.x;
  float4 f = ((const float4*)s)[i];
  short4v v;
  v[0] = (short)f2bf(f.x); v[1] = (short)f2bf(f.y);
  v[2] = (short)f2bf(f.z); v[3] = (short)f2bf(f.w);
  if (z < 3) {
    *(short4v*)(o + z * 262144 + i * 4) = v;
  } else {                       // Wo duplicated along K: wdup[co][1024]
    int idx = i * 4, co = idx >> 9, cc = idx & 511;
    short* base = o + 786432 + co * 1024 + cc;
    *(short4v*)base = v;
    *(short4v*)(base + 512) = v;
  }
}

// --------------------------------------------------- transpose inp -> x_t bf16
__global__ __launch_bounds__(256) void transpose_x_kernel(
    const float* __restrict__ inp, short* __restrict__ xt) {
  __shared__ float t[32][33];
  int tx = threadIdx.x, ty = threadIdx.y;
  int n0 = blockIdx.x * 32, c0 = blockIdx.y * 32, b = blockIdx.z;
  const float* src = inp + ((size_t)(b * 512 + c0)) * 4096 + n0;
#pragma unroll
  for (int r = 0; r < 4; ++r) t[ty + r * 8][tx] = src[(ty + r * 8) * 4096 + tx];
  __syncthreads();
  short* dst = xt + ((size_t)((b << 12) + n0)) * 512 + c0;
#pragma unroll
  for (int r = 0; r < 4; ++r) dst[(ty + r * 8) * 512 + tx] = (short)f2bf(t[tx][ty + r * 8]);
}

// ------------------------------------------------- QKV projection (fine core)
// 384 blocks 1D; xt panel's 6 consumers co-located per XCD (R5 mapping).
__global__ __launch_bounds__(512, 2) void kqv256_kernel(
    const short* __restrict__ xt,
    const short* __restrict__ wk, const short* __restrict__ wq, const short* __restrict__ wv,
    const float* __restrict__ bk, const float* __restrict__ bq, const float* __restrict__ bv,
    short* __restrict__ kt, short* __restrict__ qt, short* __restrict__ vc) {
  extern __shared__ char sm[];
  const int bid = blockIdx.x;
  const int xcd = bid & 7, s = bid >> 3;         // s: 0..47
  const int pg = s / 6, t = s % 6;
  const int panel = pg * 8 + xcd;                // 0..63
  const int z = (t < 4) ? (t >> 1) : 2;
  const short *A, *B;
  int arow0, brow0;
  if (z < 2) {
    arow0 = panel * 256; brow0 = (t & 1) * 256;
    A = xt + (size_t)arow0 * 512;
    B = ((z == 0) ? wk : wq) + (size_t)brow0 * 512;
  } else {
    arow0 = (t - 4) * 256; brow0 = panel * 256;
    A = wv + (size_t)arow0 * 512;
    B = xt + (size_t)brow0 * 512;
  }
  f32x4 acc[8][4] = {};
  gemm256_fine(A, 512, B, 512, 8, sm, acc);
  const int tid = threadIdx.x, w = tid >> 6, lane = tid & 63;
  const int gq = lane >> 4, l15 = lane & 15;
  const int wm = w >> 2, wn = w & 3;
#pragma unroll
  for (int mf = 0; mf < 8; ++mf)
#pragma unroll
    for (int nf = 0; nf < 4; ++nf)
#pragma unroll
      for (int r = 0; r < 4; ++r) {
        int row = wm * 128 + mf * 16 + gq * 4 + r;
        int col = wn * 64 + nf * 16 + l15;
        float v = acc[mf][nf][r], val;
        if (z == 0)      val = (v + bk[brow0 + col]) * QSCALE;
        else if (z == 1) val = v + bq[brow0 + col];
        else             val = v + bv[arow0 + row];
        BOUNCE256_WRITE(sm, row, col * 2, (short)f2bf(val));
      }
  short* gbase; int pitch;
  if (z == 0)      { gbase = kt + (size_t)arow0 * 512 + brow0; pitch = 512; }
  else if (z == 1) { gbase = qt + (size_t)arow0 * 512 + brow0; pitch = 512; }
  else             { gbase = vc + (size_t)arow0 * 16384 + brow0; pitch = 16384; }
  bounce256_flush(sm, gbase, pitch);
}

// ---------------------------------------- S-GEMM fine core + exp2 + row partials
// 1024 blocks 1D. xcd = (b,h) (R5 mapping, FETCH-verified).
__global__ __launch_bounds__(512, 2) void gemm_s256_kernel(
    const short* __restrict__ kt, const short* __restrict__ qt,
    short* __restrict__ P, float* __restrict__ Lpart) {
  extern __shared__ char sm[];
  const int bid = blockIdx.x;
  const int xcd = bid & 7, s = bid >> 3;         // s: 0..127
  const int b = xcd >> 1, h = xcd & 1;
  const int jt0 = (s & 7) * 256, i0 = (s >> 3) * 256;
  const short* A = kt + ((size_t)(b << 12) + i0) * 512;
  const short* B = qt + ((size_t)((b << 12) + h * 2048 + jt0)) * 512;
  f32x4 acc[8][4] = {};
  gemm256_fine(A, 512, B, 512, 8, sm, acc);
  const int tid = threadIdx.x, w = tid >> 6, lane = tid & 63;
  const int gq = lane >> 4, l15 = lane & 15;
  const int wm = w >> 2, wn = w & 3;
  const int jp = (h * 2048 + jt0 + wn * 64) >> 6;
  float* Lp = Lpart + (((size_t)b * 64 + jp) << 12) + i0 + wm * 128;
#pragma unroll
  for (int mf = 0; mf < 8; ++mf) {
    float psum[4] = {0.f, 0.f, 0.f, 0.f};
#pragma unroll
    for (int nf = 0; nf < 4; ++nf)
#pragma unroll
      for (int r = 0; r < 4; ++r) {
        float p = exp2f(acc[mf][nf][r]);
        psum[r] += p;
        int row = wm * 128 + mf * 16 + gq * 4 + r;
        int colb = (wn * 64 + nf * 16 + l15) * 2;
        BOUNCE256_WRITE(sm, row, colb, (short)f2bf(p));
      }
#pragma unroll
    for (int r = 0; r < 4; ++r) {
      float ss = psum[r];
      ss += __shfl_xor(ss, 1); ss += __shfl_xor(ss, 2);
      ss += __shfl_xor(ss, 4); ss += __shfl_xor(ss, 8);
      if (l15 == 0) Lp[mf * 16 + gq * 4 + r] = ss;
    }
  }
  short* gbase = P + (size_t)h * 33554432 + ((size_t)((b << 12) + i0)) * 2048 + jt0;
  bounce256_flush(sm, gbase, 2048);
}

// --------------------------------------------------------- PV-GEMM fine core
// 256 blocks 1D. Each XCD owns one (b,h) (R5 mapping).
__global__ __launch_bounds__(512, 2) void gemm_pv256_kernel(
    const short* __restrict__ P, const short* __restrict__ vc,
    short* __restrict__ otab) {
  extern __shared__ char sm[];
  const int bid = blockIdx.x;
  const int xcd = bid & 7, s = bid >> 3;         // s: 0..31
  const int b = xcd >> 1, h = xcd & 1;
  const int c0 = (s & 1) * 256, i0 = (s >> 1) * 256;
  const short* A = P + (size_t)h * 33554432 + ((size_t)((b << 12) + i0)) * 2048;
  const short* B = vc + (size_t)c0 * 16384 + (b << 12) + h * 2048;
  f32x4 acc[8][4] = {};
  gemm256_fine(A, 2048, B, 16384, 32, sm, acc);
  const int tid = threadIdx.x, w = tid >> 6, lane = tid & 63;
  const int gq = lane >> 4, l15 = lane & 15;
  const int wm = w >> 2, wn = w & 3;
#pragma unroll
  for (int mf = 0; mf < 8; ++mf)
#pragma unroll
    for (int nf = 0; nf < 4; ++nf)
#pragma unroll
      for (int r = 0; r < 4; ++r) {
        int row = wm * 128 + mf * 16 + gq * 4 + r;
        int colb = (wn * 64 + nf * 16 + l15) * 2;
        BOUNCE256_WRITE(sm, row, colb, (short)f2bf(acc[mf][nf][r]));
      }
  short* gbase = otab + ((size_t)((b << 12) + i0)) * 1024 + h * 512 + c0;
  bounce256_flush(sm, gbase, 1024);
}

// ------------------------------------------------------------------ l reduce
__global__ __launch_bounds__(256) void lred_kernel(
    const float* __restrict__ Lpart, float* __restrict__ linv) {
  int i = blockIdx.x * 256 + threadIdx.x;      // 16384 = (b,i)
  int b = i >> 12;
  float s = 0.f;
#pragma unroll 8
  for (int jp = 0; jp < 64; ++jp) s += Lpart[(((size_t)b * 64 + jp) << 12) + (i & 4095)];
  linv[i] = 1.0f / s;
}

// ------------------------------------------------ final projection (fine core)
// 128 blocks 1D: xcd = (b, co-half); 16 n-tiles per XCD share the wdup panel.
__global__ __launch_bounds__(512, 2) void out256_kernel(
    const short* __restrict__ wdup, const short* __restrict__ otab,
    const float* __restrict__ bo, const float* __restrict__ linv,
    float* __restrict__ out) {
  extern __shared__ char sm[];
  const int bid = blockIdx.x;
  const int xcd = bid & 7, nt = bid >> 3;       // nt: 0..15
  const int b = xcd >> 1, cot = xcd & 1;
  const int arow0 = cot * 256;                  // co
  const int bn0 = nt * 256;                     // n within batch
  const short* A = wdup + (size_t)arow0 * 1024;
  const short* B = otab + ((size_t)((b << 12) + bn0)) * 1024;
  f32x4 acc[8][4] = {};
  gemm256_fine(A, 1024, B, 1024, 16, sm, acc);
  const int tid = threadIdx.x, w = tid >> 6, lane = tid & 63;
  const int gq = lane >> 4, l15 = lane & 15;
  const int wm = w >> 2, wn = w & 3;
#pragma unroll
  for (int mf = 0; mf < 8; ++mf) {
    int co = arow0 + wm * 128 + mf * 16 + gq * 4;
#pragma unroll
    for (int nf = 0; nf < 4; ++nf) {
      int nl = bn0 + wn * 64 + nf * 16 + l15;
      float li = linv[(b << 12) + nl];
#pragma unroll
      for (int r = 0; r < 4; ++r)
        out[((size_t)(b * 512 + co + r) << 12) + nl] = acc[mf][nf][r] * li + bo[co + r];
    }
  }
}

// ---------------------------------------------------------------------- host
extern "C" void kernel_launch(void* const* d_in, const int* in_sizes, int n_in,
                              void* d_out, int out_size, void* d_ws, size_t ws_size,
                              hipStream_t stream) {
  const float* inp = (const float*)d_in[0];
  const float* Wk = (const float*)d_in[1];
  const float* bk = (const float*)d_in[2];
  const float* Wq = (const float*)d_in[3];
  const float* bq = (const float*)d_in[4];
  const float* Wv = (const float*)d_in[5];
  const float* bv = (const float*)d_in[6];
  const float* Wo = (const float*)d_in[7];
  const float* bo = (const float*)d_in[8];
  float* out = (float*)d_out;
  char* ws = (char*)d_ws;
  const size_t MB = 1048576;
  // layout (227 MB): kt 0..16 | qt 16..32 | vc 32..48 | wb 48..51
  //   xt 51..67 (dead after kqv; Lpart/linv alias) | P 67..195 | otab 195..227
  short* kt    = (short*)(ws);
  short* qt    = (short*)(ws + 16 * MB);
  short* vc    = (short*)(ws + 32 * MB);
  short* wb    = (short*)(ws + 48 * MB);
  short* xt    = (short*)(ws + 51 * MB);
  float* Lpart = (float*)(ws + 51 * MB);
  float* linv  = (float*)(ws + 55 * MB);
  short* P     = (short*)(ws + 67 * MB);
  short* otab  = (short*)(ws + 195 * MB);

  (void)in_sizes; (void)n_in; (void)out_size; (void)ws_size;

  hipFuncSetAttribute((const void*)kqv256_kernel,
                      hipFuncAttributeMaxDynamicSharedMemorySize, 131072);
  hipFuncSetAttribute((const void*)gemm_s256_kernel,
                      hipFuncAttributeMaxDynamicSharedMemorySize, 131072);
  hipFuncSetAttribute((const void*)gemm_pv256_kernel,
                      hipFuncAttributeMaxDynamicSharedMemorySize, 131072);
  hipFuncSetAttribute((const void*)out256_kernel,
                      hipFuncAttributeMaxDynamicSharedMemorySize, 131072);

  cvt_w_kernel<<<dim3(256, 4), 256, 0, stream>>>(Wk, Wq, Wv, Wo, wb);
  transpose_x_kernel<<<dim3(128, 16, 4), dim3(32, 8, 1), 0, stream>>>(inp, xt);
  kqv256_kernel<<<384, 512, 131072, stream>>>(
      xt, wb, wb + 262144, wb + 524288, bk, bq, bv, kt, qt, vc);
  gemm_s256_kernel<<<1024, 512, 131072, stream>>>(kt, qt, P, Lpart);
  gemm_pv256_kernel<<<256, 512, 131072, stream>>>(P, vc, otab);
  lred_kernel<<<64, 256, 0, stream>>>(Lpart, linv);
  out256_kernel<<<128, 512, 131072, stream>>>(wb + 786432, otab, bo, linv, out);
}